// Round 9
// baseline (468.957 us; speedup 1.0000x reference)
//
#include <hip/hip_runtime.h>
#include <math.h>

#define NLVL 16
#define NDENSE 5
#define NHASH 11
#define MAXP (1u << 19)
#define HMASK (MAXP - 1u)
#define NXCD 8
#define PPB 512   // points per task-block (256 threads x 2 points)

typedef float    f32x2 __attribute__((ext_vector_type(2)));
typedef float    f32x4 __attribute__((ext_vector_type(4)));
typedef float    f32x4u __attribute__((ext_vector_type(4), aligned(8)));
typedef _Float16 f16x2 __attribute__((ext_vector_type(2)));
typedef _Float16 f16x4 __attribute__((ext_vector_type(4)));

struct LP {
    float        scale[NLVL];
    unsigned int res[NLVL];
    unsigned int hsize[NLVL];
    unsigned int offset[NLVL];
    unsigned int hashed[NLVL];
};

struct LPH {                 // hashed levels only (l = 5..15)
    float        scale[NHASH];
    unsigned int off[NHASH];
};

// Precomputed per-point hashed-level state (static-index arrays -> registers).
struct HashPt {
    float wx, wy, wz, ux, uy, uz;
    unsigned int idx0[4], idx1[4];   // x-corner pair indices per (dy,dz)
};

__device__ __forceinline__ void hash_prep(
    float x, float y, float z, float s, HashPt& P)
{
    const float px = x * s, py = y * s, pz = z * s;
    const float gx = floorf(px), gy = floorf(py), gz = floorf(pz);
    P.wx = px - gx; P.wy = py - gy; P.wz = pz - gz;
    P.ux = 1.0f - P.wx; P.uy = 1.0f - P.wy; P.uz = 1.0f - P.wz;
    const unsigned int bx = (unsigned int)(int)gx;
    const unsigned int by = (unsigned int)(int)gy;
    const unsigned int bz = (unsigned int)(int)gz;
    // tcnn fast_hash terms, uint32 wrap (adds distribute over mod 2^32)
    const unsigned int hy0 = by * 2654435761u, hy1 = hy0 + 2654435761u;
    const unsigned int hz0 = bz * 805459861u,  hz1 = hz0 + 805459861u;
    #pragma unroll
    for (int c = 0; c < 4; ++c) {
        const unsigned int hyz = ((c & 1) ? hy1 : hy0) ^ ((c >> 1) ? hz1 : hz0);
        P.idx0[c] = (bx ^ hyz) & HMASK;          // dx=0 corner
        P.idx1[c] = ((bx + 1u) ^ hyz) & HMASK;   // dx=1 corner
    }
}

// ALL hashed levels in ONE kernel, XCD-serpentine schedule (r8 structure).
// Branchless gather: per (dy,dz) corner issue ONE dwordx4 covering the
// aligned pair {idx0&~1, |1} plus ONE dwordx2 at idx1. Even bx: the x2 load
// hits the same 64-B line (free at L2). Odd bx: it is the required second
// line. Same L2-line profile as r8 (~6/point) but zero divergence -> all 16
// loads of a thread's two points issue back-to-back (2.7x MLP).
__global__ __launch_bounds__(256) void hash_mega_kernel(
    const float* __restrict__ in, const float* __restrict__ emb,
    f16x2* __restrict__ ws, int n, int chunks, int T, int ntask, LPH lph)
{
    const int b   = blockIdx.x;
    const int tid = (b & (NXCD - 1)) * T + (b >> 3);
    if (tid >= ntask) return;
    const int lvl   = tid / chunks;            // uniform scalar div, 0..10
    const int chunk = tid - lvl * chunks;

    const float        s   = lph.scale[lvl];
    const unsigned int off = lph.off[lvl];
    f16x2* __restrict__ wsl = ws + (size_t)lvl * (size_t)n;

    const int i0 = chunk * PPB + (int)threadIdx.x;
    const int i1 = i0 + 256;
    // clamp instead of branch: inactive lanes compute garbage, skip store
    const int c0 = i0 < n ? i0 : n - 1;
    const int c1 = i1 < n ? i1 : n - 1;

    HashPt P0, P1;
    {
        const float x = (in[3 * c0 + 0] + 1.0f) * 0.5f;
        const float y = (in[3 * c0 + 1] + 1.0f) * 0.5f;
        const float z = (in[3 * c0 + 2] + 1.0f) * 0.5f;
        hash_prep(x, y, z, s, P0);
    }
    {
        const float x = (in[3 * c1 + 0] + 1.0f) * 0.5f;
        const float y = (in[3 * c1 + 1] + 1.0f) * 0.5f;
        const float z = (in[3 * c1 + 2] + 1.0f) * 0.5f;
        hash_prep(x, y, z, s, P1);
    }

    // issue all 16 loads before any consumption (static indices -> registers)
    f32x4 vp0[4], vp1[4];
    f32x2 v10[4], v11[4];
    #pragma unroll
    for (int c = 0; c < 4; ++c) {
        vp0[c] = *(const f32x4*)(emb + (size_t)(off + (P0.idx0[c] & ~1u)) * 2u);
        v10[c] = *(const f32x2*)(emb + (size_t)(off + P0.idx1[c]) * 2u);
        vp1[c] = *(const f32x4*)(emb + (size_t)(off + (P1.idx0[c] & ~1u)) * 2u);
        v11[c] = *(const f32x2*)(emb + (size_t)(off + P1.idx1[c]) * 2u);
    }

    float a00 = 0.0f, a01 = 0.0f, a10 = 0.0f, a11 = 0.0f;
    #pragma unroll
    for (int c = 0; c < 4; ++c) {
        const unsigned int dy = c & 1u, dz = (c >> 1) & 1u;
        {
            const bool hi = (P0.idx0[c] & 1u) != 0u;
            const float f0x = hi ? vp0[c].z : vp0[c].x;
            const float f0y = hi ? vp0[c].w : vp0[c].y;
            const float wyz = (dy ? P0.wy : P0.uy) * (dz ? P0.wz : P0.uz);
            a00 = fmaf(wyz * P0.ux, f0x, a00);
            a01 = fmaf(wyz * P0.ux, f0y, a01);
            a00 = fmaf(wyz * P0.wx, v10[c].x, a00);
            a01 = fmaf(wyz * P0.wx, v10[c].y, a01);
        }
        {
            const bool hi = (P1.idx0[c] & 1u) != 0u;
            const float f0x = hi ? vp1[c].z : vp1[c].x;
            const float f0y = hi ? vp1[c].w : vp1[c].y;
            const float wyz = (dy ? P1.wy : P1.uy) * (dz ? P1.wz : P1.uz);
            a10 = fmaf(wyz * P1.ux, f0x, a10);
            a11 = fmaf(wyz * P1.ux, f0y, a11);
            a10 = fmaf(wyz * P1.wx, v11[c].x, a10);
            a11 = fmaf(wyz * P1.wx, v11[c].y, a11);
        }
    }

    // ws in f16: features are +-0.01 -> f16 abs err ~5e-6, halves ws traffic
    if (i0 < n) {
        f16x2 h = { (_Float16)a00, (_Float16)a01 };
        __builtin_nontemporal_store(h, wsl + i0);
    }
    if (i1 < n) {
        f16x2 h = { (_Float16)a10, (_Float16)a11 };
        __builtin_nontemporal_store(h, wsl + i1);
    }
}

// Dense level with x-paired corner loads (one 16-B load per (dy,dz) corner).
// No wrap: inputs in [-1,1) -> bx <= res-2 -> idx+1 < hsize.
__device__ __forceinline__ void dense_level(
    float x, float y, float z, float s, unsigned int r,
    unsigned int off, const float* __restrict__ emb, float& o0, float& o1)
{
    const float px = x * s, py = y * s, pz = z * s;
    const float gx = floorf(px), gy = floorf(py), gz = floorf(pz);
    const float wx = px - gx, wy = py - gy, wz = pz - gz;
    const float ux = 1.0f - wx, uy = 1.0f - wy, uz = 1.0f - wz;
    const unsigned int bx = (unsigned int)(int)gx;
    const unsigned int by = (unsigned int)(int)gy;
    const unsigned int bz = (unsigned int)(int)gz;
    const unsigned int ty0 = by * r,     ty1 = ty0 + r;
    const unsigned int tz0 = bz * r * r, tz1 = tz0 + r * r;
    float a0 = 0.0f, a1 = 0.0f;
    #pragma unroll
    for (int c = 0; c < 4; ++c) {
        const unsigned int dy = c & 1u, dz = (c >> 1) & 1u;
        const unsigned int idx = bx + (dy ? ty1 : ty0) + (dz ? tz1 : tz0);
        const f32x4u v = *(const f32x4u*)(emb + (size_t)(off + idx) * 2u);
        const float wyz = (dy ? wy : uy) * (dz ? wz : uz);
        a0 = fmaf(wyz * ux, v.x, a0);
        a1 = fmaf(wyz * ux, v.y, a1);
        a0 = fmaf(wyz * wx, v.z, a0);
        a1 = fmaf(wyz * wx, v.w, a1);
    }
    o0 = a0; o1 = a1;
}

// 2 points/thread: dense levels 0..4 + gather 11 f16 hashed slices from ws
// (8-B/lane coalesced) -> [N,32] point-major, regular float4 stores
// (nt out-stores caused 4x write amplification, r5).
__global__ __launch_bounds__(256) void assemble_kernel(
    const float* __restrict__ in, const float* __restrict__ emb,
    const f16x2* __restrict__ ws, float* __restrict__ out, int n, LP lp)
{
    const int t  = blockIdx.x * blockDim.x + threadIdx.x;
    const int p0 = 2 * t;
    if (p0 >= n) return;
    const int p1 = (p0 + 1 < n) ? p0 + 1 : p0;

    const float x0 = (in[3 * p0 + 0] + 1.0f) * 0.5f;
    const float y0 = (in[3 * p0 + 1] + 1.0f) * 0.5f;
    const float z0 = (in[3 * p0 + 2] + 1.0f) * 0.5f;
    const float x1 = (in[3 * p1 + 0] + 1.0f) * 0.5f;
    const float y1 = (in[3 * p1 + 1] + 1.0f) * 0.5f;
    const float z1 = (in[3 * p1 + 2] + 1.0f) * 0.5f;

    float f0[2 * NLVL], f1[2 * NLVL];
    #pragma unroll
    for (int l = 0; l < NDENSE; ++l) {
        dense_level(x0, y0, z0, lp.scale[l], lp.res[l],
                    lp.offset[l], emb, f0[2 * l], f0[2 * l + 1]);
        dense_level(x1, y1, z1, lp.scale[l], lp.res[l],
                    lp.offset[l], emb, f1[2 * l], f1[2 * l + 1]);
    }

    #pragma unroll
    for (int l = NDENSE; l < NLVL; ++l) {
        // adjacent points -> one 8-B load covers both f16x2 entries
        const f16x4 v = *(const f16x4*)(
            ws + (size_t)(l - NDENSE) * (size_t)n + p0);
        f0[2 * l + 0] = (float)v.x;
        f0[2 * l + 1] = (float)v.y;
        f1[2 * l + 0] = (float)v.z;
        f1[2 * l + 1] = (float)v.w;
    }

    float4* o0 = (float4*)(out + (size_t)p0 * 32);
    #pragma unroll
    for (int j = 0; j < 8; ++j)
        o0[j] = make_float4(f0[4*j+0], f0[4*j+1], f0[4*j+2], f0[4*j+3]);
    if (p1 != p0) {
        float4* o1 = (float4*)(out + (size_t)p1 * 32);
        #pragma unroll
        for (int j = 0; j < 8; ++j)
            o1[j] = make_float4(f1[4*j+0], f1[4*j+1], f1[4*j+2], f1[4*j+3]);
    }
}

// Known-good fallback (round-1 structure) if ws is too small.
__global__ __launch_bounds__(256) void grid_enc_fallback(
    const float* __restrict__ in, const float* __restrict__ emb,
    float* __restrict__ out, int n, LP lp)
{
    const int i = blockIdx.x * blockDim.x + threadIdx.x;
    if (i >= n) return;
    const float x = (in[3 * i + 0] + 1.0f) * 0.5f;
    const float y = (in[3 * i + 1] + 1.0f) * 0.5f;
    const float z = (in[3 * i + 2] + 1.0f) * 0.5f;
    float fout[2 * NLVL];
    #pragma unroll
    for (int l = 0; l < NLVL; ++l) {
        const float s  = lp.scale[l];
        const float px = x * s, py = y * s, pz = z * s;
        const float gx = floorf(px), gy = floorf(py), gz = floorf(pz);
        const float wx = px - gx, wy = py - gy, wz = pz - gz;
        const unsigned int bx = (unsigned int)(int)gx;
        const unsigned int by = (unsigned int)(int)gy;
        const unsigned int bz = (unsigned int)(int)gz;
        const unsigned int r = lp.res[l], hs = lp.hsize[l], off = lp.offset[l];
        const bool hashed = (lp.hashed[l] != 0u);
        float a0 = 0.0f, a1 = 0.0f;
        #pragma unroll
        for (int c = 0; c < 8; ++c) {
            const unsigned int dx = c & 1u, dy = (c >> 1) & 1u, dz = (c >> 2) & 1u;
            const unsigned int ix = bx + dx, iy = by + dy, iz = bz + dz;
            unsigned int idx;
            if (hashed) {
                idx = (ix ^ (iy * 2654435761u) ^ (iz * 805459861u)) & (hs - 1u);
            } else {
                idx = ix + iy * r + iz * r * r;
                if (idx >= hs) idx -= hs;
            }
            const float2 f = *(const float2*)(emb + (size_t)(off + idx) * 2u);
            const float w = (dx ? wx : 1.0f - wx) *
                            (dy ? wy : 1.0f - wy) *
                            (dz ? wz : 1.0f - wz);
            a0 = fmaf(w, f.x, a0);
            a1 = fmaf(w, f.y, a1);
        }
        fout[2 * l + 0] = a0;
        fout[2 * l + 1] = a1;
    }
    float4* o4 = (float4*)(out + (size_t)i * 32);
    #pragma unroll
    for (int j = 0; j < 8; ++j)
        o4[j] = make_float4(fout[4*j+0], fout[4*j+1],
                            fout[4*j+2], fout[4*j+3]);
}

extern "C" void kernel_launch(void* const* d_in, const int* in_sizes, int n_in,
                              void* d_out, int out_size, void* d_ws, size_t ws_size,
                              hipStream_t stream)
{
    const float* in  = (const float*)d_in[0];
    const float* emb = (const float*)d_in[1];
    float* out = (float*)d_out;
    const int n = in_sizes[0] / 3;

    // Per-level params, f64 exactly as the Python reference.
    LP lp;
    unsigned int offset = 0;
    const double log2s = log2(1.3819);
    for (int l = 0; l < NLVL; ++l) {
        const double scale = pow(2.0, (double)l * log2s) * 16.0 - 1.0;
        const int res = (int)ceil(scale) + 1;
        const long long r3 = (long long)res * res * res;
        const bool dense = (r3 <= (long long)MAXP);
        long long pil = dense ? r3 : (long long)MAXP;
        pil = (pil + 7) / 8 * 8;
        lp.scale[l]  = (float)scale;
        lp.res[l]    = (unsigned int)res;
        lp.hsize[l]  = (unsigned int)pil;
        lp.offset[l] = offset;
        lp.hashed[l] = dense ? 0u : 1u;
        offset += (unsigned int)pil;
    }

    LPH lph;
    for (int h = 0; h < NHASH; ++h) {
        lph.scale[h] = lp.scale[NDENSE + h];
        lph.off[h]   = lp.offset[NDENSE + h];
    }

    const int block = 256;
    const size_t ws_need = (size_t)NHASH * (size_t)n * sizeof(f16x2);

    if (ws_size >= ws_need) {
        f16x2* ws = (f16x2*)d_ws;
        const int chunks = (n + PPB - 1) / PPB;
        const int ntask  = NHASH * chunks;
        const int T      = (ntask + NXCD - 1) / NXCD;
        const int mgrid  = NXCD * T;
        hash_mega_kernel<<<mgrid, block, 0, stream>>>(
            in, emb, ws, n, chunks, T, ntask, lph);
        const int agrid = (n / 2 + block - 1) / block + 1;
        assemble_kernel<<<agrid, block, 0, stream>>>(in, emb, ws, out, n, lp);
    } else {
        const int grid = (n + block - 1) / block;
        grid_enc_fallback<<<grid, block, 0, stream>>>(in, emb, out, n, lp);
    }
}

// Round 10
// 334.983 us; speedup vs baseline: 1.3999x; 1.3999x over previous
//
#include <hip/hip_runtime.h>
#include <math.h>

#define NLVL 16
#define NDENSE 5
#define NHASH 11
#define MAXP (1u << 19)
#define HMASK (MAXP - 1u)
#define NXCD 8
#define PPB 512   // points per task-block (256 threads x 2 points)

typedef float    f32x2 __attribute__((ext_vector_type(2)));
typedef float    f32x4 __attribute__((ext_vector_type(4)));
typedef float    f32x4u __attribute__((ext_vector_type(4), aligned(8)));
typedef _Float16 f16x2 __attribute__((ext_vector_type(2)));
typedef _Float16 f16x4 __attribute__((ext_vector_type(4)));

struct LP {
    float        scale[NLVL];
    unsigned int res[NLVL];
    unsigned int hsize[NLVL];
    unsigned int offset[NLVL];
    unsigned int hashed[NLVL];
};

struct LPH {                 // hashed levels only (l = 5..15)
    float scale[NHASH];
};

// ---- table convert: hashed region of emb (f32x2) -> f16x2 in ws ----------
// 2 entries/thread: one 16-B f32x4 load -> one 8-B f16x4 store.
__global__ __launch_bounds__(256) void convert_kernel(
    const float* __restrict__ emb, _Float16* __restrict__ tab16,
    unsigned int hash_base, unsigned int nent)
{
    const unsigned int e0 = 2u * (blockIdx.x * blockDim.x + threadIdx.x);
    if (e0 >= nent) return;
    const f32x4 v = *(const f32x4*)(emb + (size_t)(hash_base + e0) * 2u);
    f16x4 h = { (_Float16)v.x, (_Float16)v.y, (_Float16)v.z, (_Float16)v.w };
    *(f16x4*)(tab16 + (size_t)e0 * 2u) = h;
}

// One hashed-level evaluation for one point against the f16 table.
// r8's divergent structure (6 tx/pt avg — the measured optimum): even bx ->
// 4x 8-B paired loads; odd bx -> 8x 4-B loads. f16 table halves the bytes
// and line-touches per tx and shrinks the hot table to 2 MiB per L2.
__device__ __forceinline__ void hash_point(
    float x, float y, float z, float s,
    const _Float16* __restrict__ tab, float& o0, float& o1)
{
    const float px = x * s, py = y * s, pz = z * s;
    const float gx = floorf(px), gy = floorf(py), gz = floorf(pz);
    const float wx = px - gx, wy = py - gy, wz = pz - gz;
    const float ux = 1.0f - wx, uy = 1.0f - wy, uz = 1.0f - wz;
    const unsigned int bx = (unsigned int)(int)gx;
    const unsigned int by = (unsigned int)(int)gy;
    const unsigned int bz = (unsigned int)(int)gz;
    // tcnn fast_hash terms, uint32 wrap (adds distribute over mod 2^32)
    const unsigned int hy0 = by * 2654435761u, hy1 = hy0 + 2654435761u;
    const unsigned int hz0 = bz * 805459861u,  hz1 = hz0 + 805459861u;
    float a0 = 0.0f, a1 = 0.0f;
    if (!(bx & 1u)) {
        #pragma unroll
        for (int c = 0; c < 4; ++c) {
            const unsigned int dy = c & 1u, dz = (c >> 1) & 1u;
            const unsigned int hyz = (dy ? hy1 : hy0) ^ (dz ? hz1 : hz0);
            const unsigned int idx0 = (bx ^ hyz) & HMASK;
            const unsigned int base = idx0 & ~1u;      // 8-B aligned f16 pair
            const f16x4 v = *(const f16x4*)(tab + (size_t)base * 2u);
            const bool hi = (idx0 & 1u) != 0u;
            const float f0x = (float)(hi ? v.z : v.x);
            const float f0y = (float)(hi ? v.w : v.y);
            const float f1x = (float)(hi ? v.x : v.z);
            const float f1y = (float)(hi ? v.y : v.w);
            const float wyz = (dy ? wy : uy) * (dz ? wz : uz);
            a0 = fmaf(wyz * ux, f0x, a0);
            a1 = fmaf(wyz * ux, f0y, a1);
            a0 = fmaf(wyz * wx, f1x, a0);
            a1 = fmaf(wyz * wx, f1y, a1);
        }
    } else {
        #pragma unroll
        for (int c = 0; c < 8; ++c) {
            const unsigned int dx = c & 1u, dy = (c >> 1) & 1u, dz = (c >> 2) & 1u;
            const unsigned int idx =
                ((bx + dx) ^ (dy ? hy1 : hy0) ^ (dz ? hz1 : hz0)) & HMASK;
            const f16x2 f = *(const f16x2*)(tab + (size_t)idx * 2u);
            const float w = (dx ? wx : ux) * (dy ? wy : uy) * (dz ? wz : uz);
            a0 = fmaf(w, (float)f.x, a0);
            a1 = fmaf(w, (float)f.y, a1);
        }
    }
    o0 = a0; o1 = a1;
}

// ALL hashed levels in ONE kernel, XCD-serpentine schedule (r8 structure):
// blocks land on XCD (blockIdx % 8); block b runs task (b%8)*T + b/8 so each
// XCD sweeps a contiguous task range -> one 2-MiB f16 table hot per L2.
__global__ __launch_bounds__(256) void hash_mega_kernel(
    const float* __restrict__ in, const _Float16* __restrict__ tab16,
    f16x2* __restrict__ ws, int n, int chunks, int T, int ntask, LPH lph)
{
    const int b   = blockIdx.x;
    const int tid = (b & (NXCD - 1)) * T + (b >> 3);
    if (tid >= ntask) return;
    const int lvl   = tid / chunks;            // uniform scalar div, 0..10
    const int chunk = tid - lvl * chunks;

    const float s = lph.scale[lvl];
    const _Float16* __restrict__ tab = tab16 + (size_t)lvl * (MAXP * 2u);
    f16x2* __restrict__ wsl = ws + (size_t)lvl * (size_t)n;

    const int i0 = chunk * PPB + (int)threadIdx.x;
    const int i1 = i0 + 256;

    if (i0 < n) {
        const float x = (in[3 * i0 + 0] + 1.0f) * 0.5f;
        const float y = (in[3 * i0 + 1] + 1.0f) * 0.5f;
        const float z = (in[3 * i0 + 2] + 1.0f) * 0.5f;
        float a0, a1;
        hash_point(x, y, z, s, tab, a0, a1);
        f16x2 h = { (_Float16)a0, (_Float16)a1 };
        __builtin_nontemporal_store(h, wsl + i0);
    }
    if (i1 < n) {
        const float x = (in[3 * i1 + 0] + 1.0f) * 0.5f;
        const float y = (in[3 * i1 + 1] + 1.0f) * 0.5f;
        const float z = (in[3 * i1 + 2] + 1.0f) * 0.5f;
        float a0, a1;
        hash_point(x, y, z, s, tab, a0, a1);
        f16x2 h = { (_Float16)a0, (_Float16)a1 };
        __builtin_nontemporal_store(h, wsl + i1);
    }
}

// Dense level with x-paired corner loads (one 16-B load per (dy,dz) corner).
// No wrap: inputs in [-1,1) -> bx <= res-2 -> idx+1 < hsize.
__device__ __forceinline__ void dense_level(
    float x, float y, float z, float s, unsigned int r,
    unsigned int off, const float* __restrict__ emb, float& o0, float& o1)
{
    const float px = x * s, py = y * s, pz = z * s;
    const float gx = floorf(px), gy = floorf(py), gz = floorf(pz);
    const float wx = px - gx, wy = py - gy, wz = pz - gz;
    const float ux = 1.0f - wx, uy = 1.0f - wy, uz = 1.0f - wz;
    const unsigned int bx = (unsigned int)(int)gx;
    const unsigned int by = (unsigned int)(int)gy;
    const unsigned int bz = (unsigned int)(int)gz;
    const unsigned int ty0 = by * r,     ty1 = ty0 + r;
    const unsigned int tz0 = bz * r * r, tz1 = tz0 + r * r;
    float a0 = 0.0f, a1 = 0.0f;
    #pragma unroll
    for (int c = 0; c < 4; ++c) {
        const unsigned int dy = c & 1u, dz = (c >> 1) & 1u;
        const unsigned int idx = bx + (dy ? ty1 : ty0) + (dz ? tz1 : tz0);
        const f32x4u v = *(const f32x4u*)(emb + (size_t)(off + idx) * 2u);
        const float wyz = (dy ? wy : uy) * (dz ? wz : uz);
        a0 = fmaf(wyz * ux, v.x, a0);
        a1 = fmaf(wyz * ux, v.y, a1);
        a0 = fmaf(wyz * wx, v.z, a0);
        a1 = fmaf(wyz * wx, v.w, a1);
    }
    o0 = a0; o1 = a1;
}

// Dense levels 0..4 (f32 originals, cache-resident) + gather 11 f16 hashed
// slices from ws -> [N,32] point-major, regular float4 stores (nt out-stores
// caused 4x write amplification, r5).
__global__ __launch_bounds__(256) void assemble_kernel(
    const float* __restrict__ in, const float* __restrict__ emb,
    const f16x2* __restrict__ ws, float* __restrict__ out, int n, LP lp)
{
    const int i = blockIdx.x * blockDim.x + threadIdx.x;
    if (i >= n) return;
    const float x = (in[3 * i + 0] + 1.0f) * 0.5f;
    const float y = (in[3 * i + 1] + 1.0f) * 0.5f;
    const float z = (in[3 * i + 2] + 1.0f) * 0.5f;

    float fout[2 * NLVL];
    #pragma unroll
    for (int l = 0; l < NDENSE; ++l)
        dense_level(x, y, z, lp.scale[l], lp.res[l],
                    lp.offset[l], emb, fout[2 * l], fout[2 * l + 1]);

    #pragma unroll
    for (int l = NDENSE; l < NLVL; ++l) {
        const f16x2 v = ws[(size_t)(l - NDENSE) * (size_t)n + i];
        fout[2 * l + 0] = (float)v.x;
        fout[2 * l + 1] = (float)v.y;
    }

    float4* o4 = (float4*)(out + (size_t)i * 32);
    #pragma unroll
    for (int j = 0; j < 8; ++j)
        o4[j] = make_float4(fout[4*j+0], fout[4*j+1],
                            fout[4*j+2], fout[4*j+3]);
}

// Known-good fallback (round-1 structure) if ws is too small.
__global__ __launch_bounds__(256) void grid_enc_fallback(
    const float* __restrict__ in, const float* __restrict__ emb,
    float* __restrict__ out, int n, LP lp)
{
    const int i = blockIdx.x * blockDim.x + threadIdx.x;
    if (i >= n) return;
    const float x = (in[3 * i + 0] + 1.0f) * 0.5f;
    const float y = (in[3 * i + 1] + 1.0f) * 0.5f;
    const float z = (in[3 * i + 2] + 1.0f) * 0.5f;
    float fout[2 * NLVL];
    #pragma unroll
    for (int l = 0; l < NLVL; ++l) {
        const float s  = lp.scale[l];
        const float px = x * s, py = y * s, pz = z * s;
        const float gx = floorf(px), gy = floorf(py), gz = floorf(pz);
        const float wx = px - gx, wy = py - gy, wz = pz - gz;
        const unsigned int bx = (unsigned int)(int)gx;
        const unsigned int by = (unsigned int)(int)gy;
        const unsigned int bz = (unsigned int)(int)gz;
        const unsigned int r = lp.res[l], hs = lp.hsize[l], off = lp.offset[l];
        const bool hashed = (lp.hashed[l] != 0u);
        float a0 = 0.0f, a1 = 0.0f;
        #pragma unroll
        for (int c = 0; c < 8; ++c) {
            const unsigned int dx = c & 1u, dy = (c >> 1) & 1u, dz = (c >> 2) & 1u;
            const unsigned int ix = bx + dx, iy = by + dy, iz = bz + dz;
            unsigned int idx;
            if (hashed) {
                idx = (ix ^ (iy * 2654435761u) ^ (iz * 805459861u)) & (hs - 1u);
            } else {
                idx = ix + iy * r + iz * r * r;
                if (idx >= hs) idx -= hs;
            }
            const float2 f = *(const float2*)(emb + (size_t)(off + idx) * 2u);
            const float w = (dx ? wx : 1.0f - wx) *
                            (dy ? wy : 1.0f - wy) *
                            (dz ? wz : 1.0f - wz);
            a0 = fmaf(w, f.x, a0);
            a1 = fmaf(w, f.y, a1);
        }
        fout[2 * l + 0] = a0;
        fout[2 * l + 1] = a1;
    }
    float4* o4 = (float4*)(out + (size_t)i * 32);
    #pragma unroll
    for (int j = 0; j < 8; ++j)
        o4[j] = make_float4(fout[4*j+0], fout[4*j+1],
                            fout[4*j+2], fout[4*j+3]);
}

extern "C" void kernel_launch(void* const* d_in, const int* in_sizes, int n_in,
                              void* d_out, int out_size, void* d_ws, size_t ws_size,
                              hipStream_t stream)
{
    const float* in  = (const float*)d_in[0];
    const float* emb = (const float*)d_in[1];
    float* out = (float*)d_out;
    const int n = in_sizes[0] / 3;

    // Per-level params, f64 exactly as the Python reference.
    LP lp;
    unsigned int offset = 0;
    const double log2s = log2(1.3819);
    for (int l = 0; l < NLVL; ++l) {
        const double scale = pow(2.0, (double)l * log2s) * 16.0 - 1.0;
        const int res = (int)ceil(scale) + 1;
        const long long r3 = (long long)res * res * res;
        const bool dense = (r3 <= (long long)MAXP);
        long long pil = dense ? r3 : (long long)MAXP;
        pil = (pil + 7) / 8 * 8;
        lp.scale[l]  = (float)scale;
        lp.res[l]    = (unsigned int)res;
        lp.hsize[l]  = (unsigned int)pil;
        lp.offset[l] = offset;
        lp.hashed[l] = dense ? 0u : 1u;
        offset += (unsigned int)pil;
    }

    LPH lph;
    for (int h = 0; h < NHASH; ++h) lph.scale[h] = lp.scale[NDENSE + h];

    const unsigned int hash_base = lp.offset[NDENSE];      // 330952
    const unsigned int nent = NHASH * MAXP;                // 5,767,168
    const size_t tab_bytes = (size_t)nent * 2u * sizeof(_Float16); // 23 MB
    const size_t ws_need = tab_bytes + (size_t)NHASH * (size_t)n * sizeof(f16x2);

    const int block = 256;

    if (ws_size >= ws_need) {
        _Float16* tab16 = (_Float16*)d_ws;
        f16x2* ws = (f16x2*)((char*)d_ws + tab_bytes);

        const int cgrid = (int)((nent / 2 + block - 1) / block);
        convert_kernel<<<cgrid, block, 0, stream>>>(emb, tab16, hash_base, nent);

        const int chunks = (n + PPB - 1) / PPB;
        const int ntask  = NHASH * chunks;
        const int T      = (ntask + NXCD - 1) / NXCD;
        const int mgrid  = NXCD * T;
        hash_mega_kernel<<<mgrid, block, 0, stream>>>(
            in, tab16, ws, n, chunks, T, ntask, lph);

        const int agrid = (n + block - 1) / block;
        assemble_kernel<<<agrid, block, 0, stream>>>(in, emb, ws, out, n, lp);
    } else {
        const int grid = (n + block - 1) / block;
        grid_enc_fallback<<<grid, block, 0, stream>>>(in, emb, out, n, lp);
    }
}

// Round 11
// 306.964 us; speedup vs baseline: 1.5277x; 1.0913x over previous
//
#include <hip/hip_runtime.h>
#include <math.h>

#define NLVL 16
#define NDENSE 5
#define NHASH 11
#define MAXP (1u << 19)
#define HMASK (MAXP - 1u)
#define NXCD 8
#define PPB 512   // points per task-block (256 threads x 2 points)

typedef float    f32x2 __attribute__((ext_vector_type(2)));
typedef float    f32x4 __attribute__((ext_vector_type(4)));
typedef float    f32x4u __attribute__((ext_vector_type(4), aligned(8)));
typedef _Float16 f16x2 __attribute__((ext_vector_type(2)));
typedef _Float16 f16x4 __attribute__((ext_vector_type(4)));

struct LP {
    float        scale[NLVL];
    unsigned int res[NLVL];
    unsigned int hsize[NLVL];
    unsigned int offset[NLVL];
    unsigned int hashed[NLVL];
};

struct LPH {                 // hashed levels only (l = 5..15)
    float scale[NHASH];
};

// ---- table convert: hashed region of emb (f32x2) -> f16x2 in ws ----------
__global__ __launch_bounds__(256) void convert_kernel(
    const float* __restrict__ emb, _Float16* __restrict__ tab16,
    unsigned int hash_base, unsigned int nent)
{
    const unsigned int e0 = 2u * (blockIdx.x * blockDim.x + threadIdx.x);
    if (e0 >= nent) return;
    const f32x4 v = *(const f32x4*)(emb + (size_t)(hash_base + e0) * 2u);
    f16x4 h = { (_Float16)v.x, (_Float16)v.y, (_Float16)v.z, (_Float16)v.w };
    *(f16x4*)(tab16 + (size_t)e0 * 2u) = h;
}

// One hashed-level evaluation for one point against the f16 table (r8's
// divergent 6-tx/pt structure — the measured optimum).
__device__ __forceinline__ void hash_point(
    float x, float y, float z, float s,
    const _Float16* __restrict__ tab, float& o0, float& o1)
{
    const float px = x * s, py = y * s, pz = z * s;
    const float gx = floorf(px), gy = floorf(py), gz = floorf(pz);
    const float wx = px - gx, wy = py - gy, wz = pz - gz;
    const float ux = 1.0f - wx, uy = 1.0f - wy, uz = 1.0f - wz;
    const unsigned int bx = (unsigned int)(int)gx;
    const unsigned int by = (unsigned int)(int)gy;
    const unsigned int bz = (unsigned int)(int)gz;
    // tcnn fast_hash terms, uint32 wrap (adds distribute over mod 2^32)
    const unsigned int hy0 = by * 2654435761u, hy1 = hy0 + 2654435761u;
    const unsigned int hz0 = bz * 805459861u,  hz1 = hz0 + 805459861u;
    float a0 = 0.0f, a1 = 0.0f;
    if (!(bx & 1u)) {
        #pragma unroll
        for (int c = 0; c < 4; ++c) {
            const unsigned int dy = c & 1u, dz = (c >> 1) & 1u;
            const unsigned int hyz = (dy ? hy1 : hy0) ^ (dz ? hz1 : hz0);
            const unsigned int idx0 = (bx ^ hyz) & HMASK;
            const unsigned int base = idx0 & ~1u;      // 8-B aligned f16 pair
            const f16x4 v = *(const f16x4*)(tab + (size_t)base * 2u);
            const bool hi = (idx0 & 1u) != 0u;
            const float f0x = (float)(hi ? v.z : v.x);
            const float f0y = (float)(hi ? v.w : v.y);
            const float f1x = (float)(hi ? v.x : v.z);
            const float f1y = (float)(hi ? v.y : v.w);
            const float wyz = (dy ? wy : uy) * (dz ? wz : uz);
            a0 = fmaf(wyz * ux, f0x, a0);
            a1 = fmaf(wyz * ux, f0y, a1);
            a0 = fmaf(wyz * wx, f1x, a0);
            a1 = fmaf(wyz * wx, f1y, a1);
        }
    } else {
        #pragma unroll
        for (int c = 0; c < 8; ++c) {
            const unsigned int dx = c & 1u, dy = (c >> 1) & 1u, dz = (c >> 2) & 1u;
            const unsigned int idx =
                ((bx + dx) ^ (dy ? hy1 : hy0) ^ (dz ? hz1 : hz0)) & HMASK;
            const f16x2 f = *(const f16x2*)(tab + (size_t)idx * 2u);
            const float w = (dx ? wx : ux) * (dy ? wy : uy) * (dz ? wz : uz);
            a0 = fmaf(w, (float)f.x, a0);
            a1 = fmaf(w, (float)f.y, a1);
        }
    }
    o0 = a0; o1 = a1;
}

// ALL hashed levels in ONE kernel, XCD-serpentine schedule (r8): blocks land
// on XCD (blockIdx % 8); block b runs task (b%8)*T + b/8 so each XCD sweeps
// a contiguous task range -> one 2-MiB f16 table hot per L2.
__global__ __launch_bounds__(256) void hash_mega_kernel(
    const float* __restrict__ in, const _Float16* __restrict__ tab16,
    f16x2* __restrict__ ws, int n, int chunks, int T, int ntask, LPH lph)
{
    const int b   = blockIdx.x;
    const int tid = (b & (NXCD - 1)) * T + (b >> 3);
    if (tid >= ntask) return;
    const int lvl   = tid / chunks;
    const int chunk = tid - lvl * chunks;

    const float s = lph.scale[lvl];
    const _Float16* __restrict__ tab = tab16 + (size_t)lvl * (MAXP * 2u);
    f16x2* __restrict__ wsl = ws + (size_t)lvl * (size_t)n;

    const int i0 = chunk * PPB + (int)threadIdx.x;
    const int i1 = i0 + 256;

    if (i0 < n) {
        const float x = (in[3 * i0 + 0] + 1.0f) * 0.5f;
        const float y = (in[3 * i0 + 1] + 1.0f) * 0.5f;
        const float z = (in[3 * i0 + 2] + 1.0f) * 0.5f;
        float a0, a1;
        hash_point(x, y, z, s, tab, a0, a1);
        f16x2 h = { (_Float16)a0, (_Float16)a1 };
        __builtin_nontemporal_store(h, wsl + i0);
    }
    if (i1 < n) {
        const float x = (in[3 * i1 + 0] + 1.0f) * 0.5f;
        const float y = (in[3 * i1 + 1] + 1.0f) * 0.5f;
        const float z = (in[3 * i1 + 2] + 1.0f) * 0.5f;
        float a0, a1;
        hash_point(x, y, z, s, tab, a0, a1);
        f16x2 h = { (_Float16)a0, (_Float16)a1 };
        __builtin_nontemporal_store(h, wsl + i1);
    }
}

// Dense level with x-paired corner loads (one 16-B load per (dy,dz) corner).
__device__ __forceinline__ void dense_level(
    float x, float y, float z, float s, unsigned int r,
    unsigned int off, const float* __restrict__ emb, float& o0, float& o1)
{
    const float px = x * s, py = y * s, pz = z * s;
    const float gx = floorf(px), gy = floorf(py), gz = floorf(pz);
    const float wx = px - gx, wy = py - gy, wz = pz - gz;
    const float ux = 1.0f - wx, uy = 1.0f - wy, uz = 1.0f - wz;
    const unsigned int bx = (unsigned int)(int)gx;
    const unsigned int by = (unsigned int)(int)gy;
    const unsigned int bz = (unsigned int)(int)gz;
    const unsigned int ty0 = by * r,     ty1 = ty0 + r;
    const unsigned int tz0 = bz * r * r, tz1 = tz0 + r * r;
    float a0 = 0.0f, a1 = 0.0f;
    #pragma unroll
    for (int c = 0; c < 4; ++c) {
        const unsigned int dy = c & 1u, dz = (c >> 1) & 1u;
        const unsigned int idx = bx + (dy ? ty1 : ty0) + (dz ? tz1 : tz0);
        const f32x4u v = *(const f32x4u*)(emb + (size_t)(off + idx) * 2u);
        const float wyz = (dy ? wy : uy) * (dz ? wz : uz);
        a0 = fmaf(wyz * ux, v.x, a0);
        a1 = fmaf(wyz * ux, v.y, a1);
        a0 = fmaf(wyz * wx, v.z, a0);
        a1 = fmaf(wyz * wx, v.w, a1);
    }
    o0 = a0; o1 = a1;
}

// Assemble v2: compute fout[32] per point, stage in LDS (XOR-swizzled),
// then write the block's 32-KB out-chunk LANE-CONTIGUOUS (each store
// instruction = 1024 contiguous bytes = 16 full lines) with nt hint.
// Rationale: point-major float4 stores scatter 64 lanes over 64 lines;
// L2 line-merge service capped assemble at ~1 TB/s (r7/r10). Contiguous
// nt stores are amplification-free (ws stores, r8-r10).
__global__ __launch_bounds__(256) void assemble_kernel(
    const float* __restrict__ in, const float* __restrict__ emb,
    const f16x2* __restrict__ ws, float* __restrict__ out, int n, LP lp)
{
    __shared__ f32x4 lds4[256 * 8];   // 32 KB
    const int tid = (int)threadIdx.x;
    const int base_pt = blockIdx.x * 256;
    const int i = base_pt + tid;
    const bool full = (base_pt + 256 <= n);

    float fout[2 * NLVL];
    if (i < n) {
        const float x = (in[3 * i + 0] + 1.0f) * 0.5f;
        const float y = (in[3 * i + 1] + 1.0f) * 0.5f;
        const float z = (in[3 * i + 2] + 1.0f) * 0.5f;

        #pragma unroll
        for (int l = 0; l < NDENSE; ++l)
            dense_level(x, y, z, lp.scale[l], lp.res[l],
                        lp.offset[l], emb, fout[2 * l], fout[2 * l + 1]);

        #pragma unroll
        for (int l = NDENSE; l < NLVL; ++l) {
            const f16x2 v = ws[(size_t)(l - NDENSE) * (size_t)n + i];
            fout[2 * l + 0] = (float)v.x;
            fout[2 * l + 1] = (float)v.y;
        }
    }

    if (full) {
        // stage: thread tid's 8 float4s at slot tid*8 + (k ^ (tid&7))
        // (XOR spreads the 128-B-stride writes across all 8 bank groups)
        #pragma unroll
        for (int k = 0; k < 8; ++k) {
            f32x4 v = { fout[4*k+0], fout[4*k+1], fout[4*k+2], fout[4*k+3] };
            lds4[(tid << 3) + (k ^ (tid & 7))] = v;
        }
        __syncthreads();
        // drain: wave w writes 8 KB contiguous; lane l, iter j reads the
        // inverse-swizzled slot (same involution)
        const int w = tid >> 6, l = tid & 63;
        f32x4* ob = (f32x4*)(out + (size_t)base_pt * 32);
        #pragma unroll
        for (int j = 0; j < 8; ++j) {
            const int idx = w * 512 + j * 64 + l;     // linear float4 index
            const int pt = idx >> 3, k0 = idx & 7;
            const f32x4 v = lds4[(pt << 3) + (k0 ^ (pt & 7))];
            __builtin_nontemporal_store(v, ob + idx);
        }
    } else if (i < n) {
        // tail block: guarded per-point strided stores (old path)
        float4* o4 = (float4*)(out + (size_t)i * 32);
        #pragma unroll
        for (int j = 0; j < 8; ++j)
            o4[j] = make_float4(fout[4*j+0], fout[4*j+1],
                                fout[4*j+2], fout[4*j+3]);
    }
}

// Known-good fallback (round-1 structure) if ws is too small.
__global__ __launch_bounds__(256) void grid_enc_fallback(
    const float* __restrict__ in, const float* __restrict__ emb,
    float* __restrict__ out, int n, LP lp)
{
    const int i = blockIdx.x * blockDim.x + threadIdx.x;
    if (i >= n) return;
    const float x = (in[3 * i + 0] + 1.0f) * 0.5f;
    const float y = (in[3 * i + 1] + 1.0f) * 0.5f;
    const float z = (in[3 * i + 2] + 1.0f) * 0.5f;
    float fout[2 * NLVL];
    #pragma unroll
    for (int l = 0; l < NLVL; ++l) {
        const float s  = lp.scale[l];
        const float px = x * s, py = y * s, pz = z * s;
        const float gx = floorf(px), gy = floorf(py), gz = floorf(pz);
        const float wx = px - gx, wy = py - gy, wz = pz - gz;
        const unsigned int bx = (unsigned int)(int)gx;
        const unsigned int by = (unsigned int)(int)gy;
        const unsigned int bz = (unsigned int)(int)gz;
        const unsigned int r = lp.res[l], hs = lp.hsize[l], off = lp.offset[l];
        const bool hashed = (lp.hashed[l] != 0u);
        float a0 = 0.0f, a1 = 0.0f;
        #pragma unroll
        for (int c = 0; c < 8; ++c) {
            const unsigned int dx = c & 1u, dy = (c >> 1) & 1u, dz = (c >> 2) & 1u;
            const unsigned int ix = bx + dx, iy = by + dy, iz = bz + dz;
            unsigned int idx;
            if (hashed) {
                idx = (ix ^ (iy * 2654435761u) ^ (iz * 805459861u)) & (hs - 1u);
            } else {
                idx = ix + iy * r + iz * r * r;
                if (idx >= hs) idx -= hs;
            }
            const float2 f = *(const float2*)(emb + (size_t)(off + idx) * 2u);
            const float w = (dx ? wx : 1.0f - wx) *
                            (dy ? wy : 1.0f - wy) *
                            (dz ? wz : 1.0f - wz);
            a0 = fmaf(w, f.x, a0);
            a1 = fmaf(w, f.y, a1);
        }
        fout[2 * l + 0] = a0;
        fout[2 * l + 1] = a1;
    }
    float4* o4 = (float4*)(out + (size_t)i * 32);
    #pragma unroll
    for (int j = 0; j < 8; ++j)
        o4[j] = make_float4(fout[4*j+0], fout[4*j+1],
                            fout[4*j+2], fout[4*j+3]);
}

extern "C" void kernel_launch(void* const* d_in, const int* in_sizes, int n_in,
                              void* d_out, int out_size, void* d_ws, size_t ws_size,
                              hipStream_t stream)
{
    const float* in  = (const float*)d_in[0];
    const float* emb = (const float*)d_in[1];
    float* out = (float*)d_out;
    const int n = in_sizes[0] / 3;

    // Per-level params, f64 exactly as the Python reference.
    LP lp;
    unsigned int offset = 0;
    const double log2s = log2(1.3819);
    for (int l = 0; l < NLVL; ++l) {
        const double scale = pow(2.0, (double)l * log2s) * 16.0 - 1.0;
        const int res = (int)ceil(scale) + 1;
        const long long r3 = (long long)res * res * res;
        const bool dense = (r3 <= (long long)MAXP);
        long long pil = dense ? r3 : (long long)MAXP;
        pil = (pil + 7) / 8 * 8;
        lp.scale[l]  = (float)scale;
        lp.res[l]    = (unsigned int)res;
        lp.hsize[l]  = (unsigned int)pil;
        lp.offset[l] = offset;
        lp.hashed[l] = dense ? 0u : 1u;
        offset += (unsigned int)pil;
    }

    LPH lph;
    for (int h = 0; h < NHASH; ++h) lph.scale[h] = lp.scale[NDENSE + h];

    const unsigned int hash_base = lp.offset[NDENSE];      // 330952
    const unsigned int nent = NHASH * MAXP;                // 5,767,168
    const size_t tab_bytes = (size_t)nent * 2u * sizeof(_Float16); // 23 MB
    const size_t ws_need = tab_bytes + (size_t)NHASH * (size_t)n * sizeof(f16x2);

    const int block = 256;

    if (ws_size >= ws_need) {
        _Float16* tab16 = (_Float16*)d_ws;
        f16x2* ws = (f16x2*)((char*)d_ws + tab_bytes);

        const int cgrid = (int)((nent / 2 + block - 1) / block);
        convert_kernel<<<cgrid, block, 0, stream>>>(emb, tab16, hash_base, nent);

        const int chunks = (n + PPB - 1) / PPB;
        const int ntask  = NHASH * chunks;
        const int T      = (ntask + NXCD - 1) / NXCD;
        const int mgrid  = NXCD * T;
        hash_mega_kernel<<<mgrid, block, 0, stream>>>(
            in, tab16, ws, n, chunks, T, ntask, lph);

        const int agrid = (n + block - 1) / block;
        assemble_kernel<<<agrid, block, 0, stream>>>(in, emb, ws, out, n, lp);
    } else {
        const int grid = (n + block - 1) / block;
        grid_enc_fallback<<<grid, block, 0, stream>>>(in, emb, out, n, lp);
    }
}